// Round 1
// baseline (2171.439 us; speedup 1.0000x reference)
//
#include <hip/hip_runtime.h>
#include <math.h>

#define WWIN 9
#define BATCH 256
#define FEAT 51
#define TT 459          // WWIN*FEAT
#define EMBD 6
#define HID 306
#define G3 918
#define FFND 12
#define TOPM 80

__device__ __forceinline__ float leakyf(float v){ return v >= 0.f ? v : 0.01f*v; }
__device__ __forceinline__ float sigmf(float v){ return 1.f/(1.f+expf(-v)); }

// monotonic float->uint key (order-preserving); +-0 collapse to one key
__device__ __forceinline__ unsigned fkey(float s){
    unsigned fb = __float_as_uint(s);
    if ((fb << 1) == 0u) return 0x80000000u;
    return (fb & 0x80000000u) ? ~fb : (fb | 0x80000000u);
}

// ---------------- embedding + QKV ----------------
__global__ __launch_bounds__(256) void embed_qkv(
    const float* __restrict__ src,
    const float* __restrict__ w1w, const float* __restrict__ w1b,
    const float* __restrict__ w2w, const float* __restrict__ w2b,
    const float* __restrict__ meta,
    const float* __restrict__ Wq, const float* __restrict__ bq,
    const float* __restrict__ Wk, const float* __restrict__ bk,
    const float* __restrict__ Wv, const float* __restrict__ bv,
    float* __restrict__ X, float* __restrict__ Q,
    float* __restrict__ K, float* __restrict__ V)
{
    int idx = blockIdx.x*256 + threadIdx.x;
    if (idx >= BATCH*TT) return;
    int b = idx / TT, t = idx % TT;
    int w = t / FEAT, f = t % FEAT;
    float s = src[(w*BATCH + b)*FEAT + f];

    float h1[EMBD], h2[EMBD];
    #pragma unroll
    for (int i=0;i<EMBD;i++) h1[i] = leakyf(s*w1w[f*EMBD+i] + w1b[f*EMBD+i]);
    #pragma unroll
    for (int j=0;j<EMBD;j++){
        float a = 0.f;
        #pragma unroll
        for (int i=0;i<EMBD;i++) a += h1[i]*w2w[(f*EMBD+j)*EMBD+i];
        h2[j] = a + w2b[f*EMBD+j];
    }
    // softmax((h2 + 0.5*h1)/1e-5)
    float z[EMBD];
    float m = -INFINITY;
    #pragma unroll
    for (int j=0;j<EMBD;j++){ z[j] = (h2[j] + 0.5f*h1[j]) / 1e-05f; m = fmaxf(m, z[j]); }
    float se = 0.f;
    #pragma unroll
    for (int j=0;j<EMBD;j++){ z[j] = expf(z[j]-m); se += z[j]; }
    #pragma unroll
    for (int j=0;j<EMBD;j++) z[j] /= se;

    float xr[EMBD];
    #pragma unroll
    for (int e=0;e<EMBD;e++){
        float a = 0.f;
        #pragma unroll
        for (int i=0;i<EMBD;i++) a += z[i]*meta[(f*EMBD+i)*EMBD+e];
        xr[e] = a * 2.449489742783178f;   // sqrt(6)
    }
    float* xp = X + (b*TT + t)*EMBD;
    float* qp = Q + (b*TT + t)*EMBD;
    float* kp = K + (b*TT + t)*EMBD;
    float* vp = V + (b*TT + t)*EMBD;
    #pragma unroll
    for (int e=0;e<EMBD;e++){
        xp[e] = xr[e];
        float aq=0.f, ak=0.f, av=0.f;
        #pragma unroll
        for (int i=0;i<EMBD;i++){
            aq += xr[i]*Wq[e*EMBD+i];
            ak += xr[i]*Wk[e*EMBD+i];
            av += xr[i]*Wv[e*EMBD+i];
        }
        qp[e] = aq + bq[e];
        kp[e] = ak + bk[e];
        vp[e] = av + bv[e];
    }
}

// ---------------- attention with exact top-80 masking ----------------
__global__ __launch_bounds__(256) void attn_topk(
    const float* __restrict__ Q, const float* __restrict__ K,
    const float* __restrict__ V, float* __restrict__ O)
{
    __shared__ float kx[TT], ky[TT], vx[TT], vy[TT];
    int blk = blockIdx.x;
    int b = blk / 3, h = blk % 3;
    const int base = b*TT*EMBD + 2*h;
    for (int t = threadIdx.x; t < TT; t += 256){
        kx[t] = K[base + t*EMBD];
        ky[t] = K[base + t*EMBD + 1];
        vx[t] = V[base + t*EMBD];
        vy[t] = V[base + t*EMBD + 1];
    }
    __syncthreads();
    int wave = threadIdx.x >> 6, lane = threadIdx.x & 63;
    for (int r = wave; r < TT; r += 4){
        float q0 = Q[base + r*EMBD], q1 = Q[base + r*EMBD + 1];
        float sv[8]; unsigned uk[8];
        #pragma unroll
        for (int i=0;i<8;i++){
            int j = lane + (i<<6);
            if (j < TT){
                float p0 = q0*kx[j];
                float p1 = q1*ky[j];
                sv[i] = (p0 + p1) / 1.4142135623730951f;
            } else sv[i] = -INFINITY;
            uk[i] = fkey(sv[i]);
        }
        // radix-select the 80th-largest key (exact, duplicate-aware)
        unsigned prefix = 0; int need = TOPM;
        for (int bit = 31; bit >= 0; --bit){
            unsigned tgt = (prefix >> bit) | 1u;
            int c = 0;
            #pragma unroll
            for (int i=0;i<8;i++) c += ((uk[i] >> bit) == tgt) ? 1 : 0;
            #pragma unroll
            for (int off=32; off; off>>=1) c += __shfl_xor(c, off, 64);
            if (c >= need) prefix |= (1u<<bit); else need -= c;
        }
        // masked softmax + PV
        float mx = -INFINITY;
        #pragma unroll
        for (int i=0;i<8;i++) mx = fmaxf(mx, sv[i]);
        #pragma unroll
        for (int off=32; off; off>>=1) mx = fmaxf(mx, __shfl_xor(mx, off, 64));
        float den=0.f, ox=0.f, oy=0.f;
        #pragma unroll
        for (int i=0;i<8;i++){
            int j = lane + (i<<6);
            if (j < TT && uk[i] >= prefix){
                float p = expf(sv[i] - mx);
                den += p; ox += p*vx[j]; oy += p*vy[j];
            }
        }
        #pragma unroll
        for (int off=32; off; off>>=1){
            den += __shfl_xor(den, off, 64);
            ox  += __shfl_xor(ox , off, 64);
            oy  += __shfl_xor(oy , off, 64);
        }
        if (lane == 0){
            O[base + r*EMBD]     = ox/den;
            O[base + r*EMBD + 1] = oy/den;
        }
    }
}

// ---------------- Wo + residual + LN1 + FFN + LN2 -> seq layout ----------------
__global__ __launch_bounds__(256) void post_block(
    const float* __restrict__ X, const float* __restrict__ O,
    const float* __restrict__ Wo, const float* __restrict__ bo,
    const float* __restrict__ l1s, const float* __restrict__ l1b,
    const float* __restrict__ fw1, const float* __restrict__ fb1,
    const float* __restrict__ fw2, const float* __restrict__ fb2,
    const float* __restrict__ l2s, const float* __restrict__ l2b,
    float* __restrict__ SEQ)
{
    int idx = blockIdx.x*256 + threadIdx.x;
    if (idx >= BATCH*TT) return;
    int b = idx / TT, t = idx % TT;
    const float* xr = X + (b*TT + t)*EMBD;
    const float* orow = O + (b*TT + t)*EMBD;
    float y[EMBD];
    #pragma unroll
    for (int e=0;e<EMBD;e++){
        float a = 0.f;
        #pragma unroll
        for (int e2=0;e2<EMBD;e2++) a += orow[e2]*Wo[e*EMBD+e2];
        y[e] = xr[e] + a + bo[e];
    }
    // LN1
    float mu=0.f;
    #pragma unroll
    for (int e=0;e<EMBD;e++) mu += y[e];
    mu *= (1.f/6.f);
    float var=0.f;
    #pragma unroll
    for (int e=0;e<EMBD;e++){ float d = y[e]-mu; var += d*d; }
    var *= (1.f/6.f);
    float sd = sqrtf(var + 1e-05f);
    float xn[EMBD];
    #pragma unroll
    for (int e=0;e<EMBD;e++) xn[e] = (y[e]-mu)/sd*l1s[e] + l1b[e];
    // FFN
    float hd[FFND];
    #pragma unroll
    for (int k=0;k<FFND;k++){
        float a = fb1[k];
        #pragma unroll
        for (int e=0;e<EMBD;e++) a += xn[e]*fw1[k*EMBD+e];
        hd[k] = fmaxf(a, 0.f);
    }
    float y2[EMBD];
    #pragma unroll
    for (int e=0;e<EMBD;e++){
        float a = fb2[e];
        #pragma unroll
        for (int k=0;k<FFND;k++) a += hd[k]*fw2[e*FFND+k];
        y2[e] = xn[e] + a;
    }
    // LN2
    float mu2=0.f;
    #pragma unroll
    for (int e=0;e<EMBD;e++) mu2 += y2[e];
    mu2 *= (1.f/6.f);
    float var2=0.f;
    #pragma unroll
    for (int e=0;e<EMBD;e++){ float d = y2[e]-mu2; var2 += d*d; }
    var2 *= (1.f/6.f);
    float sd2 = sqrtf(var2 + 1e-05f);
    int w = t / FEAT, ff = t % FEAT;
    float* dst = SEQ + (w*BATCH + b)*HID + ff*EMBD;
    #pragma unroll
    for (int e=0;e<EMBD;e++) dst[e] = (y2[e]-mu2)/sd2*l2s[e] + l2b[e];
}

// ---------------- weight transposes for coalesced matmuls ----------------
__global__ void transpose_w(const float* __restrict__ wih, const float* __restrict__ whh,
                            const float* __restrict__ fcw,
                            float* __restrict__ wihT, float* __restrict__ whhT,
                            float* __restrict__ fcT)
{
    int idx = blockIdx.x*256 + threadIdx.x;
    if (idx < G3*HID){
        int o = idx / HID, i = idx % HID;
        wihT[i*G3+o] = wih[idx];
        whhT[i*G3+o] = whh[idx];
    }
    if (idx < FEAT*HID){
        int f = idx / HID, i = idx % HID;
        fcT[i*FEAT+f] = fcw[idx];
    }
}

// ---------------- (rows x 306) @ (306 x 918) + bias ----------------
__global__ __launch_bounds__(256) void mm918(
    const float* __restrict__ Rm, const float* __restrict__ Wt,
    const float* __restrict__ bias, float* __restrict__ Out)
{
    __shared__ float rl[8][HID];
    int gy = blockIdx.y, gx = blockIdx.x;
    for (int idx = threadIdx.x; idx < 8*HID; idx += 256){
        int r = idx / HID, i = idx % HID;
        rl[r][i] = Rm[(gy*8 + r)*HID + i];
    }
    __syncthreads();
    int col = gx*256 + threadIdx.x;
    if (col >= G3) return;
    float acc[8] = {0,0,0,0,0,0,0,0};
    for (int i=0;i<HID;i++){
        float wv = Wt[i*G3 + col];
        #pragma unroll
        for (int r=0;r<8;r++) acc[r] += rl[r][i]*wv;
    }
    float bb = bias[col];
    #pragma unroll
    for (int r=0;r<8;r++) Out[(gy*8+r)*G3 + col] = acc[r] + bb;
}

// ---------------- GRU cell elementwise ----------------
__global__ __launch_bounds__(256) void gru_elem(
    const float* __restrict__ GIstep, const float* __restrict__ GH,
    const float* __restrict__ Hprev, float* __restrict__ H)
{
    int idx = blockIdx.x*256 + threadIdx.x;
    if (idx >= BATCH*HID) return;
    int b = idx / HID, j = idx % HID;
    const float* gi = GIstep + b*G3;
    const float* gh = GH + b*G3;
    float r = sigmf(gi[j]       + gh[j]);
    float z = sigmf(gi[HID+j]   + gh[HID+j]);
    float n = tanhf(gi[2*HID+j] + r*gh[2*HID+j]);
    float hp = Hprev[b*HID + j];
    H[b*HID + j] = (1.f - z)*n + z*hp;
}

// ---------------- final FC + sigmoid ----------------
__global__ __launch_bounds__(64) void fcn_out(
    const float* __restrict__ H, const float* __restrict__ fcT,
    const float* __restrict__ fcb, float* __restrict__ out)
{
    int b = blockIdx.x;
    int f = threadIdx.x;
    if (f >= FEAT) return;
    float acc = 0.f;
    for (int i=0;i<HID;i++) acc += H[b*HID+i]*fcT[i*FEAT+f];
    out[b*FEAT + f] = sigmf(acc + fcb[f]);
}

extern "C" void kernel_launch(void* const* d_in, const int* in_sizes, int n_in,
                              void* d_out, int out_size, void* d_ws, size_t ws_size,
                              hipStream_t stream)
{
    const float* src = (const float*)d_in[0];
    const float* w1w = (const float*)d_in[2];
    const float* w1b = (const float*)d_in[3];
    const float* w2w = (const float*)d_in[4];
    const float* w2b = (const float*)d_in[5];
    const float* meta= (const float*)d_in[6];
    const float* Wq = (const float*)d_in[7];  const float* bq = (const float*)d_in[8];
    const float* Wk = (const float*)d_in[9];  const float* bk = (const float*)d_in[10];
    const float* Wv = (const float*)d_in[11]; const float* bv = (const float*)d_in[12];
    const float* Wo = (const float*)d_in[13]; const float* bo = (const float*)d_in[14];
    const float* l1s= (const float*)d_in[15]; const float* l1b= (const float*)d_in[16];
    const float* fw1= (const float*)d_in[17]; const float* fb1= (const float*)d_in[18];
    const float* fw2= (const float*)d_in[19]; const float* fb2= (const float*)d_in[20];
    const float* l2s= (const float*)d_in[21]; const float* l2b= (const float*)d_in[22];
    const float* wih= (const float*)d_in[23]; const float* whh= (const float*)d_in[24];
    const float* bih= (const float*)d_in[25]; const float* bhh= (const float*)d_in[26];
    const float* h0 = (const float*)d_in[27];
    const float* fcw= (const float*)d_in[28]; const float* fcb= (const float*)d_in[29];

    float* ws = (float*)d_ws;
    float* X    = ws;                 // 705024
    float* Q    = X    + 705024;      // 705024
    float* K    = Q    + 705024;      // 705024
    float* V    = K    + 705024;      // 705024
    float* O    = V    + 705024;      // 705024
    float* SEQ  = O    + 705024;      // 705024 (9,256,306)
    float* GI   = SEQ  + 705024;      // 1880064 (8,256,918)
    float* GH   = GI   + 1880064;     // 235008
    float* H    = GH   + 235008;      // 78336
    float* WIHT = H    + 78336;       // 280908
    float* WHHT = WIHT + 280908;      // 280908
    float* FCNT = WHHT + 280908;      // 15606

    transpose_w<<<1098, 256, 0, stream>>>(wih, whh, fcw, WIHT, WHHT, FCNT);
    embed_qkv<<<459, 256, 0, stream>>>(src, w1w, w1b, w2w, w2b, meta,
                                       Wq,bq,Wk,bk,Wv,bv, X,Q,K,V);
    attn_topk<<<768, 256, 0, stream>>>(Q, K, V, O);
    post_block<<<459, 256, 0, stream>>>(X, O, Wo, bo, l1s, l1b,
                                        fw1, fb1, fw2, fb2, l2s, l2b, SEQ);
    {   // all 8 steps' input gates in one batched matmul (2048 rows)
        dim3 g(4, 256);
        mm918<<<g, 256, 0, stream>>>(SEQ, WIHT, bih, GI);
    }
    const float* hprev = h0;
    for (int t = 0; t < 8; ++t){
        dim3 g(4, 32);
        mm918<<<g, 256, 0, stream>>>(hprev, WHHT, bhh, GH);
        gru_elem<<<306, 256, 0, stream>>>(GI + (size_t)t*BATCH*G3, GH, hprev, H);
        hprev = H;
    }
    fcn_out<<<256, 64, 0, stream>>>(H, FCNT, fcb, (float*)d_out);
}

// Round 2
// 1146.923 us; speedup vs baseline: 1.8933x; 1.8933x over previous
//
#include <hip/hip_runtime.h>
#include <math.h>

#define WWIN 9
#define BATCH 256
#define FEAT 51
#define TT 459          // WWIN*FEAT
#define EMBD 6
#define HID 306
#define G3 918
#define FFND 12
#define TOPM 80

__device__ __forceinline__ float leakyf(float v){ return v >= 0.f ? v : 0.01f*v; }
__device__ __forceinline__ float sigmf(float v){ return 1.f/(1.f+expf(-v)); }

// monotonic float->uint key (order-preserving); +-0 collapse to one key
__device__ __forceinline__ unsigned fkey(float s){
    unsigned fb = __float_as_uint(s);
    if ((fb << 1) == 0u) return 0x80000000u;
    return (fb & 0x80000000u) ? ~fb : (fb | 0x80000000u);
}
__device__ __forceinline__ float fkey_inv(unsigned k){
    unsigned fb = (k & 0x80000000u) ? (k ^ 0x80000000u) : ~k;
    return __uint_as_float(fb);
}

// ---------------- embedding + QKV ----------------
__global__ __launch_bounds__(256) void embed_qkv(
    const float* __restrict__ src,
    const float* __restrict__ w1w, const float* __restrict__ w1b,
    const float* __restrict__ w2w, const float* __restrict__ w2b,
    const float* __restrict__ meta,
    const float* __restrict__ Wq, const float* __restrict__ bq,
    const float* __restrict__ Wk, const float* __restrict__ bk,
    const float* __restrict__ Wv, const float* __restrict__ bv,
    float* __restrict__ X, float* __restrict__ Q,
    float* __restrict__ K, float* __restrict__ V)
{
    int idx = blockIdx.x*256 + threadIdx.x;
    if (idx >= BATCH*TT) return;
    int b = idx / TT, t = idx % TT;
    int w = t / FEAT, f = t % FEAT;
    float s = src[(w*BATCH + b)*FEAT + f];

    float h1[EMBD], h2[EMBD];
    #pragma unroll
    for (int i=0;i<EMBD;i++) h1[i] = leakyf(s*w1w[f*EMBD+i] + w1b[f*EMBD+i]);
    #pragma unroll
    for (int j=0;j<EMBD;j++){
        float a = 0.f;
        #pragma unroll
        for (int i=0;i<EMBD;i++) a += h1[i]*w2w[(f*EMBD+j)*EMBD+i];
        h2[j] = a + w2b[f*EMBD+j];
    }
    // softmax((h2 + 0.5*h1)/1e-5)
    float z[EMBD];
    float m = -INFINITY;
    #pragma unroll
    for (int j=0;j<EMBD;j++){ z[j] = (h2[j] + 0.5f*h1[j]) * 1e+05f; m = fmaxf(m, z[j]); }
    float se = 0.f;
    #pragma unroll
    for (int j=0;j<EMBD;j++){ z[j] = expf(z[j]-m); se += z[j]; }
    float inv = 1.0f / se;
    #pragma unroll
    for (int j=0;j<EMBD;j++) z[j] *= inv;

    float xr[EMBD];
    #pragma unroll
    for (int e=0;e<EMBD;e++){
        float a = 0.f;
        #pragma unroll
        for (int i=0;i<EMBD;i++) a += z[i]*meta[(f*EMBD+i)*EMBD+e];
        xr[e] = a * 2.449489742783178f;   // sqrt(6)
    }
    float* xp = X + (b*TT + t)*EMBD;
    float* qp = Q + (b*TT + t)*EMBD;
    float* kp = K + (b*TT + t)*EMBD;
    float* vp = V + (b*TT + t)*EMBD;
    #pragma unroll
    for (int e=0;e<EMBD;e++){
        xp[e] = xr[e];
        float aq=0.f, ak=0.f, av=0.f;
        #pragma unroll
        for (int i=0;i<EMBD;i++){
            aq += xr[i]*Wq[e*EMBD+i];
            ak += xr[i]*Wk[e*EMBD+i];
            av += xr[i]*Wv[e*EMBD+i];
        }
        qp[e] = aq + bq[e];
        kp[e] = ak + bk[e];
        vp[e] = av + bv[e];
    }
}

// ---------------- attention with exact top-80 masking ----------------
// grid (768, 4): block = (b,h) x row-quarter. Ballot-based radix select
// with early exit; softmax offset by threshold (no row-max reduce).
__global__ __launch_bounds__(256) void attn_topk(
    const float* __restrict__ Q, const float* __restrict__ K,
    const float* __restrict__ V, float* __restrict__ O)
{
    __shared__ float2 kk[512], vv[512];
    int blk = blockIdx.x;
    int b = blk / 3, h = blk % 3;
    const int base = b*TT*EMBD + 2*h;
    for (int t = threadIdx.x; t < 512; t += 256){
        if (t < TT){
            kk[t] = make_float2(K[base + t*EMBD], K[base + t*EMBD + 1]);
            vv[t] = make_float2(V[base + t*EMBD], V[base + t*EMBD + 1]);
        } else {
            kk[t] = make_float2(0.f, 0.f);
            vv[t] = make_float2(0.f, 0.f);
        }
    }
    __syncthreads();
    int wave = threadIdx.x >> 6, lane = threadIdx.x & 63;
    int ridx = blockIdx.y*4 + wave;           // 0..15
    for (int r = ridx; r < TT; r += 16){
        float q0 = Q[base + r*EMBD], q1 = Q[base + r*EMBD + 1];
        float sv[8]; unsigned uk[8];
        #pragma unroll
        for (int i=0;i<8;i++){
            int j = lane + (i<<6);
            float2 kv = kk[j];
            float s = (q0*kv.x + q1*kv.y) * 0.7071067811865476f;
            sv[i] = (j < TT) ? s : -INFINITY;
            uk[i] = fkey(sv[i]);
        }
        // radix-select the 80th-largest key: ballot counts + early exit
        unsigned prefix = 0; int need = TOPM; int cact = 512;
        int bit = 31;
        for (; bit >= 0; --bit){
            unsigned tgt = (prefix >> bit) | 1u;
            int c = 0;
            #pragma unroll
            for (int i=0;i<8;i++)
                c += __popcll(__ballot((uk[i] >> bit) == tgt));
            if (c >= need){ prefix |= (1u<<bit); cact = c; }
            else          { need -= c; cact -= c; }
            if (cact == need) break;
        }
        unsigned kth;
        if (bit >= 0){
            // all remaining candidates are in the top set: kth = min(active)
            unsigned mn = 0xFFFFFFFFu;
            unsigned pp = prefix >> bit;
            #pragma unroll
            for (int i=0;i<8;i++)
                if ((uk[i] >> bit) == pp) mn = min(mn, uk[i]);
            #pragma unroll
            for (int off=32; off; off>>=1) mn = min(mn, __shfl_xor(mn, off, 64));
            kth = mn;
        } else {
            kth = prefix;
        }
        // masked softmax + PV, exp offset by threshold value
        float skth = fkey_inv(kth);
        float den=0.f, ox=0.f, oy=0.f;
        #pragma unroll
        for (int i=0;i<8;i++){
            if (uk[i] >= kth){
                float p = expf(sv[i] - skth);
                float2 v2 = vv[lane + (i<<6)];
                den += p; ox += p*v2.x; oy += p*v2.y;
            }
        }
        #pragma unroll
        for (int off=32; off; off>>=1){
            den += __shfl_xor(den, off, 64);
            ox  += __shfl_xor(ox , off, 64);
            oy  += __shfl_xor(oy , off, 64);
        }
        if (lane == 0){
            float id = 1.0f/den;
            O[base + r*EMBD]     = ox*id;
            O[base + r*EMBD + 1] = oy*id;
        }
    }
}

// ---------------- Wo + residual + LN1 + FFN + LN2 -> seq layout ----------------
__global__ __launch_bounds__(256) void post_block(
    const float* __restrict__ X, const float* __restrict__ O,
    const float* __restrict__ Wo, const float* __restrict__ bo,
    const float* __restrict__ l1s, const float* __restrict__ l1b,
    const float* __restrict__ fw1, const float* __restrict__ fb1,
    const float* __restrict__ fw2, const float* __restrict__ fb2,
    const float* __restrict__ l2s, const float* __restrict__ l2b,
    float* __restrict__ SEQ)
{
    int idx = blockIdx.x*256 + threadIdx.x;
    if (idx >= BATCH*TT) return;
    int b = idx / TT, t = idx % TT;
    const float* xr = X + (b*TT + t)*EMBD;
    const float* orow = O + (b*TT + t)*EMBD;
    float y[EMBD];
    #pragma unroll
    for (int e=0;e<EMBD;e++){
        float a = 0.f;
        #pragma unroll
        for (int e2=0;e2<EMBD;e2++) a += orow[e2]*Wo[e*EMBD+e2];
        y[e] = xr[e] + a + bo[e];
    }
    // LN1
    float mu=0.f;
    #pragma unroll
    for (int e=0;e<EMBD;e++) mu += y[e];
    mu *= (1.f/6.f);
    float var=0.f;
    #pragma unroll
    for (int e=0;e<EMBD;e++){ float d = y[e]-mu; var += d*d; }
    var *= (1.f/6.f);
    float isd = 1.0f / sqrtf(var + 1e-05f);
    float xn[EMBD];
    #pragma unroll
    for (int e=0;e<EMBD;e++) xn[e] = (y[e]-mu)*isd*l1s[e] + l1b[e];
    // FFN
    float hd[FFND];
    #pragma unroll
    for (int k=0;k<FFND;k++){
        float a = fb1[k];
        #pragma unroll
        for (int e=0;e<EMBD;e++) a += xn[e]*fw1[k*EMBD+e];
        hd[k] = fmaxf(a, 0.f);
    }
    float y2[EMBD];
    #pragma unroll
    for (int e=0;e<EMBD;e++){
        float a = fb2[e];
        #pragma unroll
        for (int k=0;k<FFND;k++) a += hd[k]*fw2[e*FFND+k];
        y2[e] = xn[e] + a;
    }
    // LN2
    float mu2=0.f;
    #pragma unroll
    for (int e=0;e<EMBD;e++) mu2 += y2[e];
    mu2 *= (1.f/6.f);
    float var2=0.f;
    #pragma unroll
    for (int e=0;e<EMBD;e++){ float d = y2[e]-mu2; var2 += d*d; }
    var2 *= (1.f/6.f);
    float isd2 = 1.0f / sqrtf(var2 + 1e-05f);
    int w = t / FEAT, ff = t % FEAT;
    float* dst = SEQ + (w*BATCH + b)*HID + ff*EMBD;
    #pragma unroll
    for (int e=0;e<EMBD;e++) dst[e] = (y2[e]-mu2)*isd2*l2s[e] + l2b[e];
}

// ---------------- weight transposes for coalesced matmuls ----------------
__global__ void transpose_w(const float* __restrict__ wih, const float* __restrict__ whh,
                            const float* __restrict__ fcw,
                            float* __restrict__ wihT, float* __restrict__ whhT,
                            float* __restrict__ fcT)
{
    int idx = blockIdx.x*256 + threadIdx.x;
    if (idx < G3*HID){
        int o = idx / HID, i = idx % HID;
        wihT[i*G3+o] = wih[idx];
        whhT[i*G3+o] = whh[idx];
    }
    if (idx < FEAT*HID){
        int f = idx / HID, i = idx % HID;
        fcT[i*FEAT+f] = fcw[idx];
    }
}

// ---------------- (rows x 306) @ (306 x 918) + bias ----------------
template<int RPB>
__global__ __launch_bounds__(256) void mm918(
    const float* __restrict__ Rm, const float* __restrict__ Wt,
    const float* __restrict__ bias, float* __restrict__ Out)
{
    __shared__ float rl[RPB][HID];
    int gy = blockIdx.y, gx = blockIdx.x;
    for (int idx = threadIdx.x; idx < RPB*HID; idx += 256){
        int r = idx / HID, i = idx % HID;
        rl[r][i] = Rm[(gy*RPB + r)*HID + i];
    }
    __syncthreads();
    int col = gx*256 + threadIdx.x;
    if (col >= G3) return;
    float acc[RPB];
    #pragma unroll
    for (int r=0;r<RPB;r++) acc[r] = 0.f;
    for (int i=0;i<HID;i++){
        float wv = Wt[i*G3 + col];
        #pragma unroll
        for (int r=0;r<RPB;r++) acc[r] += rl[r][i]*wv;
    }
    float bb = bias[col];
    #pragma unroll
    for (int r=0;r<RPB;r++) Out[(gy*RPB+r)*G3 + col] = acc[r] + bb;
}

// ---------------- GRU cell elementwise ----------------
__global__ __launch_bounds__(256) void gru_elem(
    const float* __restrict__ GIstep, const float* __restrict__ GH,
    const float* __restrict__ Hprev, float* __restrict__ H)
{
    int idx = blockIdx.x*256 + threadIdx.x;
    if (idx >= BATCH*HID) return;
    int b = idx / HID, j = idx % HID;
    const float* gi = GIstep + b*G3;
    const float* gh = GH + b*G3;
    float r = sigmf(gi[j]       + gh[j]);
    float z = sigmf(gi[HID+j]   + gh[HID+j]);
    float n = tanhf(gi[2*HID+j] + r*gh[2*HID+j]);
    float hp = Hprev[b*HID + j];
    H[b*HID + j] = (1.f - z)*n + z*hp;
}

// ---------------- final FC + sigmoid ----------------
__global__ __launch_bounds__(64) void fcn_out(
    const float* __restrict__ H, const float* __restrict__ fcT,
    const float* __restrict__ fcb, float* __restrict__ out)
{
    int b = blockIdx.x;
    int f = threadIdx.x;
    if (f >= FEAT) return;
    float acc = 0.f;
    for (int i=0;i<HID;i++) acc += H[b*HID+i]*fcT[i*FEAT+f];
    out[b*FEAT + f] = sigmf(acc + fcb[f]);
}

extern "C" void kernel_launch(void* const* d_in, const int* in_sizes, int n_in,
                              void* d_out, int out_size, void* d_ws, size_t ws_size,
                              hipStream_t stream)
{
    const float* src = (const float*)d_in[0];
    const float* w1w = (const float*)d_in[2];
    const float* w1b = (const float*)d_in[3];
    const float* w2w = (const float*)d_in[4];
    const float* w2b = (const float*)d_in[5];
    const float* meta= (const float*)d_in[6];
    const float* Wq = (const float*)d_in[7];  const float* bq = (const float*)d_in[8];
    const float* Wk = (const float*)d_in[9];  const float* bk = (const float*)d_in[10];
    const float* Wv = (const float*)d_in[11]; const float* bv = (const float*)d_in[12];
    const float* Wo = (const float*)d_in[13]; const float* bo = (const float*)d_in[14];
    const float* l1s= (const float*)d_in[15]; const float* l1b= (const float*)d_in[16];
    const float* fw1= (const float*)d_in[17]; const float* fb1= (const float*)d_in[18];
    const float* fw2= (const float*)d_in[19]; const float* fb2= (const float*)d_in[20];
    const float* l2s= (const float*)d_in[21]; const float* l2b= (const float*)d_in[22];
    const float* wih= (const float*)d_in[23]; const float* whh= (const float*)d_in[24];
    const float* bih= (const float*)d_in[25]; const float* bhh= (const float*)d_in[26];
    const float* h0 = (const float*)d_in[27];
    const float* fcw= (const float*)d_in[28]; const float* fcb= (const float*)d_in[29];

    float* ws = (float*)d_ws;
    float* X    = ws;                 // 705024
    float* Q    = X    + 705024;      // 705024
    float* K    = Q    + 705024;      // 705024
    float* V    = K    + 705024;      // 705024
    float* O    = V    + 705024;      // 705024
    float* SEQ  = O    + 705024;      // 705024 (9,256,306)
    float* GI   = SEQ  + 705024;      // 1880064 (8,256,918)
    float* GH   = GI   + 1880064;     // 235008
    float* H    = GH   + 235008;      // 78336
    float* WIHT = H    + 78336;       // 280908
    float* WHHT = WIHT + 280908;      // 280908
    float* FCNT = WHHT + 280908;      // 15606

    transpose_w<<<1098, 256, 0, stream>>>(wih, whh, fcw, WIHT, WHHT, FCNT);
    embed_qkv<<<459, 256, 0, stream>>>(src, w1w, w1b, w2w, w2b, meta,
                                       Wq,bq,Wk,bk,Wv,bv, X,Q,K,V);
    {
        dim3 g(768, 4);
        attn_topk<<<g, 256, 0, stream>>>(Q, K, V, O);
    }
    post_block<<<459, 256, 0, stream>>>(X, O, Wo, bo, l1s, l1b,
                                        fw1, fb1, fw2, fb2, l2s, l2b, SEQ);
    {   // all 8 steps' input gates in one batched matmul (2048 rows)
        dim3 g(4, 256);
        mm918<8><<<g, 256, 0, stream>>>(SEQ, WIHT, bih, GI);
    }
    const float* hprev = h0;
    for (int t = 0; t < 8; ++t){
        dim3 g(4, 64);
        mm918<4><<<g, 256, 0, stream>>>(hprev, WHHT, bhh, GH);
        gru_elem<<<306, 256, 0, stream>>>(GI + (size_t)t*BATCH*G3, GH, hprev, H);
        hprev = H;
    }
    fcn_out<<<256, 64, 0, stream>>>(H, FCNT, fcb, (float*)d_out);
}

// Round 3
// 1049.900 us; speedup vs baseline: 2.0682x; 1.0924x over previous
//
#include <hip/hip_runtime.h>
#include <math.h>

#define WWIN 9
#define BATCH 256
#define FEAT 51
#define TT 459          // WWIN*FEAT
#define EMBD 6
#define HID 306
#define G3 918
#define FFND 12
#define TOPM 80

__device__ __forceinline__ float leakyf(float v){ return v >= 0.f ? v : 0.01f*v; }
__device__ __forceinline__ float sigmf(float v){ return 1.f/(1.f+__expf(-v)); }

// monotonic float->uint key (order-preserving); +-0 collapse to one key
__device__ __forceinline__ unsigned fkey(float s){
    unsigned fb = __float_as_uint(s);
    if ((fb << 1) == 0u) return 0x80000000u;
    return (fb & 0x80000000u) ? ~fb : (fb | 0x80000000u);
}
__device__ __forceinline__ float fkey_inv(unsigned k){
    unsigned fb = (k & 0x80000000u) ? (k ^ 0x80000000u) : ~k;
    return __uint_as_float(fb);
}

// ---------------- embedding + QKV ----------------
__global__ __launch_bounds__(256) void embed_qkv(
    const float* __restrict__ src,
    const float* __restrict__ w1w, const float* __restrict__ w1b,
    const float* __restrict__ w2w, const float* __restrict__ w2b,
    const float* __restrict__ meta,
    const float* __restrict__ Wq, const float* __restrict__ bq,
    const float* __restrict__ Wk, const float* __restrict__ bk,
    const float* __restrict__ Wv, const float* __restrict__ bv,
    float* __restrict__ X, float* __restrict__ Q,
    float* __restrict__ K, float* __restrict__ V)
{
    int idx = blockIdx.x*256 + threadIdx.x;
    if (idx >= BATCH*TT) return;
    int b = idx / TT, t = idx % TT;
    int w = t / FEAT, f = t % FEAT;
    float s = src[(w*BATCH + b)*FEAT + f];

    float h1[EMBD], h2[EMBD];
    #pragma unroll
    for (int i=0;i<EMBD;i++) h1[i] = leakyf(s*w1w[f*EMBD+i] + w1b[f*EMBD+i]);
    #pragma unroll
    for (int j=0;j<EMBD;j++){
        float a = 0.f;
        #pragma unroll
        for (int i=0;i<EMBD;i++) a += h1[i]*w2w[(f*EMBD+j)*EMBD+i];
        h2[j] = a + w2b[f*EMBD+j];
    }
    // softmax((h2 + 0.5*h1)/1e-5)
    float z[EMBD];
    float m = -INFINITY;
    #pragma unroll
    for (int j=0;j<EMBD;j++){ z[j] = (h2[j] + 0.5f*h1[j]) * 1e+05f; m = fmaxf(m, z[j]); }
    float se = 0.f;
    #pragma unroll
    for (int j=0;j<EMBD;j++){ z[j] = expf(z[j]-m); se += z[j]; }
    float inv = 1.0f / se;
    #pragma unroll
    for (int j=0;j<EMBD;j++) z[j] *= inv;

    float xr[EMBD];
    #pragma unroll
    for (int e=0;e<EMBD;e++){
        float a = 0.f;
        #pragma unroll
        for (int i=0;i<EMBD;i++) a += z[i]*meta[(f*EMBD+i)*EMBD+e];
        xr[e] = a * 2.449489742783178f;   // sqrt(6)
    }
    float* xp = X + (b*TT + t)*EMBD;
    float* qp = Q + (b*TT + t)*EMBD;
    float* kp = K + (b*TT + t)*EMBD;
    float* vp = V + (b*TT + t)*EMBD;
    #pragma unroll
    for (int e=0;e<EMBD;e++){
        xp[e] = xr[e];
        float aq=0.f, ak=0.f, av=0.f;
        #pragma unroll
        for (int i=0;i<EMBD;i++){
            aq += xr[i]*Wq[e*EMBD+i];
            ak += xr[i]*Wk[e*EMBD+i];
            av += xr[i]*Wv[e*EMBD+i];
        }
        qp[e] = aq + bq[e];
        kp[e] = ak + bk[e];
        vp[e] = av + bv[e];
    }
}

// ---------------- attention with exact top-80 masking ----------------
// grid (768, 4); each wave interleaves TWO rows (r, r+16) for ILP.
__global__ __launch_bounds__(256) void attn_topk(
    const float* __restrict__ Q, const float* __restrict__ K,
    const float* __restrict__ V, float* __restrict__ O)
{
    __shared__ float2 kk[512], vv[512];
    int blk = blockIdx.x;
    int b = blk / 3, h = blk % 3;
    const int base = b*TT*EMBD + 2*h;
    for (int t = threadIdx.x; t < 512; t += 256){
        if (t < TT){
            kk[t] = make_float2(K[base + t*EMBD], K[base + t*EMBD + 1]);
            vv[t] = make_float2(V[base + t*EMBD], V[base + t*EMBD + 1]);
        } else {
            kk[t] = make_float2(0.f, 0.f);
            vv[t] = make_float2(0.f, 0.f);
        }
    }
    __syncthreads();
    int wave = threadIdx.x >> 6, lane = threadIdx.x & 63;
    int ridx = blockIdx.y*4 + wave;           // 0..15
    const float SC = 0.7071067811865476f;
    for (int r0 = ridx; r0 < TT; r0 += 32){
        int r1 = r0 + 16;
        bool has1 = (r1 < TT);
        float q00 = Q[base + r0*EMBD], q01 = Q[base + r0*EMBD + 1];
        float q10 = 0.f, q11 = 0.f;
        if (has1){ q10 = Q[base + r1*EMBD]; q11 = Q[base + r1*EMBD + 1]; }

        float sv0[8], sv1[8]; unsigned uk0[8], uk1[8];
        #pragma unroll
        for (int i=0;i<8;i++){
            int j = lane + (i<<6);
            float2 kv = kk[j];
            bool valid = (j < TT);
            float s0 = (q00*kv.x + q01*kv.y) * SC;
            float s1 = (q10*kv.x + q11*kv.y) * SC;
            sv0[i] = valid ? s0 : -INFINITY;
            sv1[i] = valid ? s1 : -INFINITY;
            uk0[i] = fkey(sv0[i]);
            uk1[i] = fkey(sv1[i]);
        }
        // interleaved ballot radix-select with early exit (wave-uniform state)
        unsigned pf0 = 0, pf1 = 0;
        int need0 = TOPM, need1 = TOPM, ca0 = 512, ca1 = 512;
        int done0 = 0, done1 = has1 ? 0 : 1;
        int bd0 = -1, bd1 = -1;
        for (int bit = 31; bit >= 0; --bit){
            if (!done0){
                unsigned tgt = (pf0 >> bit) | 1u;
                int c = 0;
                #pragma unroll
                for (int i=0;i<8;i++) c += __popcll(__ballot((uk0[i] >> bit) == tgt));
                if (c >= need0){ pf0 |= (1u<<bit); ca0 = c; }
                else           { need0 -= c; ca0 -= c; }
                if (ca0 == need0){ done0 = 1; bd0 = bit; }
            }
            if (!done1){
                unsigned tgt = (pf1 >> bit) | 1u;
                int c = 0;
                #pragma unroll
                for (int i=0;i<8;i++) c += __popcll(__ballot((uk1[i] >> bit) == tgt));
                if (c >= need1){ pf1 |= (1u<<bit); ca1 = c; }
                else           { need1 -= c; ca1 -= c; }
                if (ca1 == need1){ done1 = 1; bd1 = bit; }
            }
            if (done0 && done1) break;
        }
        unsigned kth0, kth1 = 0;
        if (bd0 >= 0){
            unsigned mn = 0xFFFFFFFFu, pp = pf0 >> bd0;
            #pragma unroll
            for (int i=0;i<8;i++) if ((uk0[i] >> bd0) == pp) mn = min(mn, uk0[i]);
            #pragma unroll
            for (int off=32; off; off>>=1) mn = min(mn, __shfl_xor(mn, off, 64));
            kth0 = mn;
        } else kth0 = pf0;
        if (has1){
            if (bd1 >= 0){
                unsigned mn = 0xFFFFFFFFu, pp = pf1 >> bd1;
                #pragma unroll
                for (int i=0;i<8;i++) if ((uk1[i] >> bd1) == pp) mn = min(mn, uk1[i]);
                #pragma unroll
                for (int off=32; off; off>>=1) mn = min(mn, __shfl_xor(mn, off, 64));
                kth1 = mn;
            } else kth1 = pf1;
        }
        // masked softmax + PV, exp offset by threshold value
        float skth0 = fkey_inv(kth0);
        float skth1 = has1 ? fkey_inv(kth1) : 0.f;
        float den0=0.f, ox0=0.f, oy0=0.f, den1=0.f, ox1=0.f, oy1=0.f;
        #pragma unroll
        for (int i=0;i<8;i++){
            float2 v2 = vv[lane + (i<<6)];
            if (uk0[i] >= kth0){
                float p = __expf(sv0[i] - skth0);
                den0 += p; ox0 += p*v2.x; oy0 += p*v2.y;
            }
            if (has1 && uk1[i] >= kth1){
                float p = __expf(sv1[i] - skth1);
                den1 += p; ox1 += p*v2.x; oy1 += p*v2.y;
            }
        }
        #pragma unroll
        for (int off=32; off; off>>=1){
            den0 += __shfl_xor(den0, off, 64);
            ox0  += __shfl_xor(ox0 , off, 64);
            oy0  += __shfl_xor(oy0 , off, 64);
            den1 += __shfl_xor(den1, off, 64);
            ox1  += __shfl_xor(ox1 , off, 64);
            oy1  += __shfl_xor(oy1 , off, 64);
        }
        if (lane == 0){
            float id0 = 1.0f/den0;
            O[base + r0*EMBD]     = ox0*id0;
            O[base + r0*EMBD + 1] = oy0*id0;
            if (has1){
                float id1 = 1.0f/den1;
                O[base + r1*EMBD]     = ox1*id1;
                O[base + r1*EMBD + 1] = oy1*id1;
            }
        }
    }
}

// ---------------- Wo + residual + LN1 + FFN + LN2 -> seq layout ----------------
__global__ __launch_bounds__(256) void post_block(
    const float* __restrict__ X, const float* __restrict__ O,
    const float* __restrict__ Wo, const float* __restrict__ bo,
    const float* __restrict__ l1s, const float* __restrict__ l1b,
    const float* __restrict__ fw1, const float* __restrict__ fb1,
    const float* __restrict__ fw2, const float* __restrict__ fb2,
    const float* __restrict__ l2s, const float* __restrict__ l2b,
    float* __restrict__ SEQ)
{
    int idx = blockIdx.x*256 + threadIdx.x;
    if (idx >= BATCH*TT) return;
    int b = idx / TT, t = idx % TT;
    const float* xr = X + (b*TT + t)*EMBD;
    const float* orow = O + (b*TT + t)*EMBD;
    float y[EMBD];
    #pragma unroll
    for (int e=0;e<EMBD;e++){
        float a = 0.f;
        #pragma unroll
        for (int e2=0;e2<EMBD;e2++) a += orow[e2]*Wo[e*EMBD+e2];
        y[e] = xr[e] + a + bo[e];
    }
    float mu=0.f;
    #pragma unroll
    for (int e=0;e<EMBD;e++) mu += y[e];
    mu *= (1.f/6.f);
    float var=0.f;
    #pragma unroll
    for (int e=0;e<EMBD;e++){ float d = y[e]-mu; var += d*d; }
    var *= (1.f/6.f);
    float isd = 1.0f / sqrtf(var + 1e-05f);
    float xn[EMBD];
    #pragma unroll
    for (int e=0;e<EMBD;e++) xn[e] = (y[e]-mu)*isd*l1s[e] + l1b[e];
    float hd[FFND];
    #pragma unroll
    for (int k=0;k<FFND;k++){
        float a = fb1[k];
        #pragma unroll
        for (int e=0;e<EMBD;e++) a += xn[e]*fw1[k*EMBD+e];
        hd[k] = fmaxf(a, 0.f);
    }
    float y2[EMBD];
    #pragma unroll
    for (int e=0;e<EMBD;e++){
        float a = fb2[e];
        #pragma unroll
        for (int k=0;k<FFND;k++) a += hd[k]*fw2[e*FFND+k];
        y2[e] = xn[e] + a;
    }
    float mu2=0.f;
    #pragma unroll
    for (int e=0;e<EMBD;e++) mu2 += y2[e];
    mu2 *= (1.f/6.f);
    float var2=0.f;
    #pragma unroll
    for (int e=0;e<EMBD;e++){ float d = y2[e]-mu2; var2 += d*d; }
    var2 *= (1.f/6.f);
    float isd2 = 1.0f / sqrtf(var2 + 1e-05f);
    int w = t / FEAT, ff = t % FEAT;
    float* dst = SEQ + (w*BATCH + b)*HID + ff*EMBD;
    #pragma unroll
    for (int e=0;e<EMBD;e++) dst[e] = (y2[e]-mu2)*isd2*l2s[e] + l2b[e];
}

// ---------------- weight transposes for coalesced matmuls ----------------
__global__ void transpose_w(const float* __restrict__ wih, const float* __restrict__ whh,
                            const float* __restrict__ fcw,
                            float* __restrict__ wihT, float* __restrict__ whhT,
                            float* __restrict__ fcT)
{
    int idx = blockIdx.x*256 + threadIdx.x;
    if (idx < G3*HID){
        int o = idx / HID, i = idx % HID;
        wihT[i*G3+o] = wih[idx];
        whhT[i*G3+o] = whh[idx];
    }
    if (idx < FEAT*HID){
        int f = idx / HID, i = idx % HID;
        fcT[i*FEAT+f] = fcw[idx];
    }
}

// ---------------- (rows x 306) @ (306 x 918) + bias (input gates, batched) ----------------
template<int RPB>
__global__ __launch_bounds__(256) void mm918(
    const float* __restrict__ Rm, const float* __restrict__ Wt,
    const float* __restrict__ bias, float* __restrict__ Out)
{
    __shared__ float rl[RPB][HID];
    int gy = blockIdx.y, gx = blockIdx.x;
    for (int idx = threadIdx.x; idx < RPB*HID; idx += 256){
        int r = idx / HID, i = idx % HID;
        rl[r][i] = Rm[(gy*RPB + r)*HID + i];
    }
    __syncthreads();
    int col = gx*256 + threadIdx.x;
    if (col >= G3) return;
    float acc[RPB];
    #pragma unroll
    for (int r=0;r<RPB;r++) acc[r] = 0.f;
    for (int i=0;i<HID;i++){
        float wv = Wt[i*G3 + col];
        #pragma unroll
        for (int r=0;r<RPB;r++) acc[r] += rl[r][i]*wv;
    }
    float bb = bias[col];
    #pragma unroll
    for (int r=0;r<RPB;r++) Out[(gy*RPB+r)*G3 + col] = acc[r] + bb;
}

// ---------------- fused GRU step: hidden matmul + gates ----------------
// grid (2, 128): x = j-half (153 cols), y = batch-pair. 192 threads, 153 active.
__global__ __launch_bounds__(192) void gru_step(
    const float* __restrict__ GIstep, const float* __restrict__ WhT,
    const float* __restrict__ bhh, const float* __restrict__ Hprev,
    float* __restrict__ H)
{
    __shared__ float hp[2][HID];
    int b0 = blockIdx.y*2;
    int j0 = blockIdx.x*153;
    for (int i = threadIdx.x; i < 2*HID; i += 192){
        int r = i / HID, c = i % HID;
        hp[r][c] = Hprev[(b0+r)*HID + c];
    }
    __syncthreads();
    int jl = threadIdx.x;
    if (jl >= 153) return;
    int j = j0 + jl;
    float ar0=0.f, az0=0.f, an0=0.f, ar1=0.f, az1=0.f, an1=0.f;
    for (int i=0;i<HID;i++){
        const float* wr = WhT + i*G3 + j;
        float wv_r = wr[0], wv_z = wr[306], wv_n = wr[612];
        float h0v = hp[0][i], h1v = hp[1][i];
        ar0 += h0v*wv_r; az0 += h0v*wv_z; an0 += h0v*wv_n;
        ar1 += h1v*wv_r; az1 += h1v*wv_z; an1 += h1v*wv_n;
    }
    float br = bhh[j], bz = bhh[306+j], bn = bhh[612+j];
    #pragma unroll
    for (int r=0;r<2;r++){
        int b = b0 + r;
        const float* gi = GIstep + b*G3;
        float ghr = (r? ar1:ar0) + br;
        float ghz = (r? az1:az0) + bz;
        float ghn = (r? an1:an0) + bn;
        float rr = sigmf(gi[j] + ghr);
        float zz = sigmf(gi[306+j] + ghz);
        float nn = tanhf(gi[612+j] + rr*ghn);
        H[b*HID + j] = (1.f - zz)*nn + zz*hp[r][j];
    }
}

// ---------------- final FC + sigmoid ----------------
__global__ __launch_bounds__(64) void fcn_out(
    const float* __restrict__ H, const float* __restrict__ fcT,
    const float* __restrict__ fcb, float* __restrict__ out)
{
    __shared__ float hr[HID];
    int b = blockIdx.x;
    for (int i = threadIdx.x; i < HID; i += 64) hr[i] = H[b*HID + i];
    __syncthreads();
    int f = threadIdx.x;
    if (f >= FEAT) return;
    float acc = 0.f;
    for (int i=0;i<HID;i++) acc += hr[i]*fcT[i*FEAT+f];
    out[b*FEAT + f] = sigmf(acc + fcb[f]);
}

extern "C" void kernel_launch(void* const* d_in, const int* in_sizes, int n_in,
                              void* d_out, int out_size, void* d_ws, size_t ws_size,
                              hipStream_t stream)
{
    const float* src = (const float*)d_in[0];
    const float* w1w = (const float*)d_in[2];
    const float* w1b = (const float*)d_in[3];
    const float* w2w = (const float*)d_in[4];
    const float* w2b = (const float*)d_in[5];
    const float* meta= (const float*)d_in[6];
    const float* Wq = (const float*)d_in[7];  const float* bq = (const float*)d_in[8];
    const float* Wk = (const float*)d_in[9];  const float* bk = (const float*)d_in[10];
    const float* Wv = (const float*)d_in[11]; const float* bv = (const float*)d_in[12];
    const float* Wo = (const float*)d_in[13]; const float* bo = (const float*)d_in[14];
    const float* l1s= (const float*)d_in[15]; const float* l1b= (const float*)d_in[16];
    const float* fw1= (const float*)d_in[17]; const float* fb1= (const float*)d_in[18];
    const float* fw2= (const float*)d_in[19]; const float* fb2= (const float*)d_in[20];
    const float* l2s= (const float*)d_in[21]; const float* l2b= (const float*)d_in[22];
    const float* wih= (const float*)d_in[23]; const float* whh= (const float*)d_in[24];
    const float* bih= (const float*)d_in[25]; const float* bhh= (const float*)d_in[26];
    const float* h0 = (const float*)d_in[27];
    const float* fcw= (const float*)d_in[28]; const float* fcb= (const float*)d_in[29];

    float* ws = (float*)d_ws;
    float* X    = ws;                 // 705024
    float* Q    = X    + 705024;      // 705024
    float* K    = Q    + 705024;      // 705024
    float* V    = K    + 705024;      // 705024
    float* O    = V    + 705024;      // 705024
    float* SEQ  = O    + 705024;      // 705024 (9,256,306)
    float* GI   = SEQ  + 705024;      // 1880064 (8,256,918)
    float* HA   = GI   + 1880064;     // 78336
    float* HB   = HA   + 78336;       // 78336
    float* PAD  = HB   + 78336;       // 78336 (unused)
    float* WIHT = PAD  + 78336;       // 280908
    float* WHHT = WIHT + 280908;      // 280908
    float* FCNT = WHHT + 280908;      // 15606

    transpose_w<<<1098, 256, 0, stream>>>(wih, whh, fcw, WIHT, WHHT, FCNT);
    embed_qkv<<<459, 256, 0, stream>>>(src, w1w, w1b, w2w, w2b, meta,
                                       Wq,bq,Wk,bk,Wv,bv, X,Q,K,V);
    {
        dim3 g(768, 4);
        attn_topk<<<g, 256, 0, stream>>>(Q, K, V, O);
    }
    post_block<<<459, 256, 0, stream>>>(X, O, Wo, bo, l1s, l1b,
                                        fw1, fb1, fw2, fb2, l2s, l2b, SEQ);
    {   // all 8 steps' input gates in one batched matmul (2048 rows)
        dim3 g(4, 256);
        mm918<8><<<g, 256, 0, stream>>>(SEQ, WIHT, bih, GI);
    }
    const float* hprev = h0;
    float* hbufs[2] = {HA, HB};
    for (int t = 0; t < 8; ++t){
        float* hout = hbufs[t & 1];
        dim3 g(2, 128);
        gru_step<<<g, 192, 0, stream>>>(GI + (size_t)t*BATCH*G3, WHHT, bhh, hprev, hout);
        hprev = hout;
    }
    fcn_out<<<256, 64, 0, stream>>>(hprev, FCNT, fcb, (float*)d_out);
}

// Round 4
// 367.121 us; speedup vs baseline: 5.9148x; 2.8598x over previous
//
#include <hip/hip_runtime.h>
#include <math.h>

#define WWIN 9
#define BATCH 256
#define FEAT 51
#define TT 459          // WWIN*FEAT
#define EMBD 6
#define HID 306
#define G3 918
#define FFND 12
#define TOPM 80
#define MAXTASK 320     // >= 306, padded

__device__ __forceinline__ float leakyf(float v){ return v >= 0.f ? v : 0.01f*v; }
__device__ __forceinline__ float sigmf(float v){ return 1.f/(1.f+__expf(-v)); }

// monotonic float->uint key (order-preserving), branchless
__device__ __forceinline__ unsigned fkey(float s){
    unsigned fb = __float_as_uint(s);
    unsigned m = (unsigned)((int)fb >> 31);
    return fb ^ (m | 0x80000000u);
}
__device__ __forceinline__ float fkey_inv(unsigned k){
    unsigned fb = (k & 0x80000000u) ? (k ^ 0x80000000u) : ~k;
    return __uint_as_float(fb);
}

// ---------------- embedding + QKV + bucket argmax ----------------
__global__ __launch_bounds__(256) void embed_qkv(
    const float* __restrict__ src,
    const float* __restrict__ w1w, const float* __restrict__ w1b,
    const float* __restrict__ w2w, const float* __restrict__ w2b,
    const float* __restrict__ meta,
    const float* __restrict__ Wq, const float* __restrict__ bq,
    const float* __restrict__ Wk, const float* __restrict__ bk,
    const float* __restrict__ Wv, const float* __restrict__ bv,
    float* __restrict__ X, float* __restrict__ Q,
    float* __restrict__ K, float* __restrict__ V,
    int* __restrict__ BUCK)
{
    int idx = blockIdx.x*256 + threadIdx.x;
    if (idx >= BATCH*TT) return;
    int b = idx / TT, t = idx % TT;
    int w = t / FEAT, f = t % FEAT;
    float s = src[(w*BATCH + b)*FEAT + f];

    float h1[EMBD], h2[EMBD];
    #pragma unroll
    for (int i=0;i<EMBD;i++) h1[i] = leakyf(s*w1w[f*EMBD+i] + w1b[f*EMBD+i]);
    #pragma unroll
    for (int j=0;j<EMBD;j++){
        float a = 0.f;
        #pragma unroll
        for (int i=0;i<EMBD;i++) a += h1[i]*w2w[(f*EMBD+j)*EMBD+i];
        h2[j] = a + w2b[f*EMBD+j];
    }
    // softmax((h2 + 0.5*h1)/1e-5) and argmax bucket
    float z[EMBD];
    float m = -INFINITY; int jm = 0;
    #pragma unroll
    for (int j=0;j<EMBD;j++){
        z[j] = (h2[j] + 0.5f*h1[j]) * 1e+05f;
        if (z[j] > m){ m = z[j]; jm = j; }
    }
    float se = 0.f;
    #pragma unroll
    for (int j=0;j<EMBD;j++){ z[j] = expf(z[j]-m); se += z[j]; }
    float inv = 1.0f / se;
    #pragma unroll
    for (int j=0;j<EMBD;j++) z[j] *= inv;
    BUCK[b*TT + t] = jm;

    float xr[EMBD];
    #pragma unroll
    for (int e=0;e<EMBD;e++){
        float a = 0.f;
        #pragma unroll
        for (int i=0;i<EMBD;i++) a += z[i]*meta[(f*EMBD+i)*EMBD+e];
        xr[e] = a * 2.449489742783178f;   // sqrt(6)
    }
    float* xp = X + (b*TT + t)*EMBD;
    float* qp = Q + (b*TT + t)*EMBD;
    float* kp = K + (b*TT + t)*EMBD;
    float* vp = V + (b*TT + t)*EMBD;
    #pragma unroll
    for (int e=0;e<EMBD;e++){
        xp[e] = xr[e];
        float aq=0.f, ak=0.f, av=0.f;
        #pragma unroll
        for (int i=0;i<EMBD;i++){
            aq += xr[i]*Wq[e*EMBD+i];
            ak += xr[i]*Wk[e*EMBD+i];
            av += xr[i]*Wv[e*EMBD+i];
        }
        qp[e] = aq + bq[e];
        kp[e] = ak + bk[e];
        vp[e] = av + bv[e];
    }
}

// ---------------- build distinct-row task lists (one block=wave per batch) ----------------
__global__ __launch_bounds__(64) void build_tasks(
    const int* __restrict__ BUCK, int* __restrict__ TASKS,
    int* __restrict__ ROWMAP, int* __restrict__ NT)
{
    int b = blockIdx.x;
    int f = threadIdx.x;
    unsigned mask = 0; int repw[6]; int cnt = 0;
    if (f < FEAT){
        #pragma unroll
        for (int w=0; w<WWIN; w++){
            int j = BUCK[b*TT + w*FEAT + f];
            if (!((mask>>j) & 1u)){ mask |= 1u<<j; repw[j] = w; }
        }
        cnt = __popc(mask);
    }
    // inclusive scan across the wave
    int inc = cnt;
    #pragma unroll
    for (int off=1; off<64; off<<=1){
        int n = __shfl_up(inc, off, 64);
        if (threadIdx.x >= off) inc += n;
    }
    int offset = inc - cnt;
    if (f < FEAT){
        int rk = 0;
        #pragma unroll
        for (int j=0;j<6;j++){
            if ((mask>>j) & 1u){
                TASKS[b*MAXTASK + offset + rk] = (f<<8) | (j<<4) | repw[j];
                rk++;
            }
        }
        #pragma unroll
        for (int w=0;w<WWIN;w++){
            int j = BUCK[b*TT + w*FEAT + f];
            int r = __popc(mask & ((1u<<j)-1u));
            ROWMAP[b*TT + w*FEAT + f] = offset + r;
        }
    }
    if (threadIdx.x == 63) NT[b] = inc;
}

// ---------------- attention: distinct rows only, count-ge threshold descent ----------------
// grid (768, 4): x = (b,h), y = task-quarter; 4 waves/block, 1 task per wave.
__global__ __launch_bounds__(256) void attn_topk(
    const float* __restrict__ Q, const float* __restrict__ K,
    const float* __restrict__ V, const int* __restrict__ TASKS,
    const int* __restrict__ NT, float2* __restrict__ OD)
{
    __shared__ float2 kk[512], vv[512];
    int blk = blockIdx.x;
    int b = blk / 3, h = blk % 3;
    const int base = b*TT*EMBD + 2*h;
    for (int t = threadIdx.x; t < 512; t += 256){
        if (t < TT){
            kk[t] = make_float2(K[base + t*EMBD], K[base + t*EMBD + 1]);
            vv[t] = make_float2(V[base + t*EMBD], V[base + t*EMBD + 1]);
        } else {
            kk[t] = make_float2(0.f, 0.f);
            vv[t] = make_float2(0.f, 0.f);
        }
    }
    __syncthreads();
    int nt = NT[b];
    int wave = threadIdx.x >> 6, lane = threadIdx.x & 63;
    const float SC = 0.7071067811865476f;
    for (int idx = blockIdx.y*4 + wave; idx < nt; idx += 16){
        int pk = TASKS[b*MAXTASK + idx];
        int rep_t = (pk & 15)*FEAT + (pk >> 8);
        float q0 = Q[base + rep_t*EMBD]     * SC;
        float q1 = Q[base + rep_t*EMBD + 1] * SC;

        float sv[8]; unsigned uk[8];
        #pragma unroll
        for (int i=0;i<8;i++){
            int j = lane + (i<<6);
            float2 kv = kk[j];
            float s = q0*kv.x + q1*kv.y;
            sv[i] = s;
            uk[i] = (j < TT) ? fkey(s) : 0u;   // pads: key 0, never selected
        }
        // binary descent on threshold value: after bit b, T = kth bits 31..b
        unsigned T = 0; int exact = 0;
        for (int bit = 31; bit >= 0; --bit){
            unsigned Tp = T | (1u<<bit);
            int c = 0;
            #pragma unroll
            for (int i=0;i<8;i++) c += __popcll(__ballot(uk[i] >= Tp));
            if (c >= TOPM) T = Tp;
            if (c == TOPM){ exact = 1; break; }
        }
        unsigned kth;
        if (exact){
            unsigned mn = 0xFFFFFFFFu;
            #pragma unroll
            for (int i=0;i<8;i++) if (uk[i] >= T) mn = min(mn, uk[i]);
            #pragma unroll
            for (int off=32; off; off>>=1) mn = min(mn, __shfl_xor(mn, off, 64));
            kth = mn;
        } else {
            kth = T;
        }
        // masked softmax + PV, exp offset by threshold value
        float skth = fkey_inv(kth);
        float den=0.f, ox=0.f, oy=0.f;
        #pragma unroll
        for (int i=0;i<8;i++){
            float2 v2 = vv[lane + (i<<6)];
            float p = __expf(sv[i] - skth);
            p = (uk[i] >= kth) ? p : 0.f;
            den += p; ox += p*v2.x; oy += p*v2.y;
        }
        #pragma unroll
        for (int off=32; off; off>>=1){
            den += __shfl_xor(den, off, 64);
            ox  += __shfl_xor(ox , off, 64);
            oy  += __shfl_xor(oy , off, 64);
        }
        if (lane == 0){
            float id = 1.0f/den;
            OD[(b*3 + h)*MAXTASK + idx] = make_float2(ox*id, oy*id);
        }
    }
}

// ---------------- Wo + residual + LN1 + FFN + LN2 -> seq layout (gathers O via ROWMAP) ----------------
__global__ __launch_bounds__(256) void post_block(
    const float* __restrict__ X, const float2* __restrict__ OD,
    const int* __restrict__ ROWMAP,
    const float* __restrict__ Wo, const float* __restrict__ bo,
    const float* __restrict__ l1s, const float* __restrict__ l1b,
    const float* __restrict__ fw1, const float* __restrict__ fb1,
    const float* __restrict__ fw2, const float* __restrict__ fb2,
    const float* __restrict__ l2s, const float* __restrict__ l2b,
    float* __restrict__ SEQ)
{
    int idx = blockIdx.x*256 + threadIdx.x;
    if (idx >= BATCH*TT) return;
    int b = idx / TT, t = idx % TT;
    const float* xr = X + (b*TT + t)*EMBD;
    int rm = ROWMAP[b*TT + t];
    float orow[EMBD];
    #pragma unroll
    for (int h=0;h<3;h++){
        float2 od = OD[(b*3 + h)*MAXTASK + rm];
        orow[2*h]   = od.x;
        orow[2*h+1] = od.y;
    }
    float y[EMBD];
    #pragma unroll
    for (int e=0;e<EMBD;e++){
        float a = 0.f;
        #pragma unroll
        for (int e2=0;e2<EMBD;e2++) a += orow[e2]*Wo[e*EMBD+e2];
        y[e] = xr[e] + a + bo[e];
    }
    float mu=0.f;
    #pragma unroll
    for (int e=0;e<EMBD;e++) mu += y[e];
    mu *= (1.f/6.f);
    float var=0.f;
    #pragma unroll
    for (int e=0;e<EMBD;e++){ float d = y[e]-mu; var += d*d; }
    var *= (1.f/6.f);
    float isd = 1.0f / sqrtf(var + 1e-05f);
    float xn[EMBD];
    #pragma unroll
    for (int e=0;e<EMBD;e++) xn[e] = (y[e]-mu)*isd*l1s[e] + l1b[e];
    float hd[FFND];
    #pragma unroll
    for (int k=0;k<FFND;k++){
        float a = fb1[k];
        #pragma unroll
        for (int e=0;e<EMBD;e++) a += xn[e]*fw1[k*EMBD+e];
        hd[k] = fmaxf(a, 0.f);
    }
    float y2[EMBD];
    #pragma unroll
    for (int e=0;e<EMBD;e++){
        float a = fb2[e];
        #pragma unroll
        for (int k=0;k<FFND;k++) a += hd[k]*fw2[e*FFND+k];
        y2[e] = xn[e] + a;
    }
    float mu2=0.f;
    #pragma unroll
    for (int e=0;e<EMBD;e++) mu2 += y2[e];
    mu2 *= (1.f/6.f);
    float var2=0.f;
    #pragma unroll
    for (int e=0;e<EMBD;e++){ float d = y2[e]-mu2; var2 += d*d; }
    var2 *= (1.f/6.f);
    float isd2 = 1.0f / sqrtf(var2 + 1e-05f);
    int w = t / FEAT, ff = t % FEAT;
    float* dst = SEQ + (w*BATCH + b)*HID + ff*EMBD;
    #pragma unroll
    for (int e=0;e<EMBD;e++) dst[e] = (y2[e]-mu2)*isd2*l2s[e] + l2b[e];
}

// ---------------- weight transposes ----------------
__global__ void transpose_w(const float* __restrict__ wih, const float* __restrict__ whh,
                            const float* __restrict__ fcw,
                            float* __restrict__ wihT, float* __restrict__ whhT,
                            float* __restrict__ fcT)
{
    int idx = blockIdx.x*256 + threadIdx.x;
    if (idx < G3*HID){
        int o = idx / HID, i = idx % HID;
        wihT[i*G3+o] = wih[idx];
        whhT[i*G3+o] = whh[idx];
    }
    if (idx < FEAT*HID){
        int f = idx / HID, i = idx % HID;
        fcT[i*FEAT+f] = fcw[idx];
    }
}

// ---------------- (rows x 306) @ (306 x 918) + bias (input gates, batched) ----------------
template<int RPB>
__global__ __launch_bounds__(256) void mm918(
    const float* __restrict__ Rm, const float* __restrict__ Wt,
    const float* __restrict__ bias, float* __restrict__ Out)
{
    __shared__ float rl[RPB][HID];
    int gy = blockIdx.y, gx = blockIdx.x;
    for (int idx = threadIdx.x; idx < RPB*HID; idx += 256){
        int r = idx / HID, i = idx % HID;
        rl[r][i] = Rm[(gy*RPB + r)*HID + i];
    }
    __syncthreads();
    int col = gx*256 + threadIdx.x;
    if (col >= G3) return;
    float acc[RPB];
    #pragma unroll
    for (int r=0;r<RPB;r++) acc[r] = 0.f;
    for (int i=0;i<HID;i++){
        float wv = Wt[i*G3 + col];
        #pragma unroll
        for (int r=0;r<RPB;r++) acc[r] += rl[r][i]*wv;
    }
    float bb = bias[col];
    #pragma unroll
    for (int r=0;r<RPB;r++) Out[(gy*RPB+r)*G3 + col] = acc[r] + bb;
}

// ---------------- fused GRU step: hidden matmul + gates ----------------
__global__ __launch_bounds__(192) void gru_step(
    const float* __restrict__ GIstep, const float* __restrict__ WhT,
    const float* __restrict__ bhh, const float* __restrict__ Hprev,
    float* __restrict__ H)
{
    __shared__ float hp[2][HID];
    int b0 = blockIdx.y*2;
    int j0 = blockIdx.x*153;
    for (int i = threadIdx.x; i < 2*HID; i += 192){
        int r = i / HID, c = i % HID;
        hp[r][c] = Hprev[(b0+r)*HID + c];
    }
    __syncthreads();
    int jl = threadIdx.x;
    if (jl >= 153) return;
    int j = j0 + jl;
    float ar0=0.f, az0=0.f, an0=0.f, ar1=0.f, az1=0.f, an1=0.f;
    for (int i=0;i<HID;i++){
        const float* wr = WhT + i*G3 + j;
        float wv_r = wr[0], wv_z = wr[306], wv_n = wr[612];
        float h0v = hp[0][i], h1v = hp[1][i];
        ar0 += h0v*wv_r; az0 += h0v*wv_z; an0 += h0v*wv_n;
        ar1 += h1v*wv_r; az1 += h1v*wv_z; an1 += h1v*wv_n;
    }
    float br = bhh[j], bz = bhh[306+j], bn = bhh[612+j];
    #pragma unroll
    for (int r=0;r<2;r++){
        int b = b0 + r;
        const float* gi = GIstep + b*G3;
        float ghr = (r? ar1:ar0) + br;
        float ghz = (r? az1:az0) + bz;
        float ghn = (r? an1:an0) + bn;
        float rr = sigmf(gi[j] + ghr);
        float zz = sigmf(gi[306+j] + ghz);
        float nn = tanhf(gi[612+j] + rr*ghn);
        H[b*HID + j] = (1.f - zz)*nn + zz*hp[r][j];
    }
}

// ---------------- final FC + sigmoid ----------------
__global__ __launch_bounds__(64) void fcn_out(
    const float* __restrict__ H, const float* __restrict__ fcT,
    const float* __restrict__ fcb, float* __restrict__ out)
{
    __shared__ float hr[HID];
    int b = blockIdx.x;
    for (int i = threadIdx.x; i < HID; i += 64) hr[i] = H[b*HID + i];
    __syncthreads();
    int f = threadIdx.x;
    if (f >= FEAT) return;
    float acc = 0.f;
    for (int i=0;i<HID;i++) acc += hr[i]*fcT[i*FEAT+f];
    out[b*FEAT + f] = sigmf(acc + fcb[f]);
}

extern "C" void kernel_launch(void* const* d_in, const int* in_sizes, int n_in,
                              void* d_out, int out_size, void* d_ws, size_t ws_size,
                              hipStream_t stream)
{
    const float* src = (const float*)d_in[0];
    const float* w1w = (const float*)d_in[2];
    const float* w1b = (const float*)d_in[3];
    const float* w2w = (const float*)d_in[4];
    const float* w2b = (const float*)d_in[5];
    const float* meta= (const float*)d_in[6];
    const float* Wq = (const float*)d_in[7];  const float* bq = (const float*)d_in[8];
    const float* Wk = (const float*)d_in[9];  const float* bk = (const float*)d_in[10];
    const float* Wv = (const float*)d_in[11]; const float* bv = (const float*)d_in[12];
    const float* Wo = (const float*)d_in[13]; const float* bo = (const float*)d_in[14];
    const float* l1s= (const float*)d_in[15]; const float* l1b= (const float*)d_in[16];
    const float* fw1= (const float*)d_in[17]; const float* fb1= (const float*)d_in[18];
    const float* fw2= (const float*)d_in[19]; const float* fb2= (const float*)d_in[20];
    const float* l2s= (const float*)d_in[21]; const float* l2b= (const float*)d_in[22];
    const float* wih= (const float*)d_in[23]; const float* whh= (const float*)d_in[24];
    const float* bih= (const float*)d_in[25]; const float* bhh= (const float*)d_in[26];
    const float* h0 = (const float*)d_in[27];
    const float* fcw= (const float*)d_in[28]; const float* fcb= (const float*)d_in[29];

    float* ws = (float*)d_ws;
    float* X    = ws;                  // 705024
    float* Q    = X    + 705024;       // 705024
    float* K    = Q    + 705024;       // 705024
    float* V    = K    + 705024;       // 705024
    float* SEQ  = V    + 705024;       // 705024 (9,256,306)
    float* GI   = SEQ  + 705024;       // 1880064 (8,256,918)
    float* HA   = GI   + 1880064;      // 78336
    float* HB   = HA   + 78336;        // 78336
    float* WIHT = HB   + 78336;        // 280908
    float* WHHT = WIHT + 280908;       // 280908
    float* FCNT = WHHT + 280908;       // 15606
    float* ODf  = FCNT + 15606;        // 491520 (float2 x 256*3*320)
    int*   BUCK = (int*)(ODf + 491520);    // 117504
    int*   TASKS= BUCK + 117504;           // 81920
    int*   RMAP = TASKS + 81920;           // 117504
    int*   NT   = RMAP + 117504;           // 256
    float2* OD  = (float2*)ODf;

    transpose_w<<<1098, 256, 0, stream>>>(wih, whh, fcw, WIHT, WHHT, FCNT);
    embed_qkv<<<459, 256, 0, stream>>>(src, w1w, w1b, w2w, w2b, meta,
                                       Wq,bq,Wk,bk,Wv,bv, X,Q,K,V, BUCK);
    build_tasks<<<256, 64, 0, stream>>>(BUCK, TASKS, RMAP, NT);
    {
        dim3 g(768, 4);
        attn_topk<<<g, 256, 0, stream>>>(Q, K, V, TASKS, NT, OD);
    }
    post_block<<<459, 256, 0, stream>>>(X, OD, RMAP, Wo, bo, l1s, l1b,
                                        fw1, fb1, fw2, fb2, l2s, l2b, SEQ);
    {   // all 8 steps' input gates in one batched matmul (2048 rows)
        dim3 g(4, 256);
        mm918<8><<<g, 256, 0, stream>>>(SEQ, WIHT, bih, GI);
    }
    const float* hprev = h0;
    float* hbufs[2] = {HA, HB};
    for (int t = 0; t < 8; ++t){
        float* hout = hbufs[t & 1];
        dim3 g(2, 128);
        gru_step<<<g, 192, 0, stream>>>(GI + (size_t)t*BATCH*G3, WHHT, bhh, hprev, hout);
        hprev = hout;
    }
    fcn_out<<<256, 64, 0, stream>>>(hprev, FCNT, fcb, (float*)d_out);
}